// Round 1
// baseline (1149.042 us; speedup 1.0000x reference)
//
#include <hip/hip_runtime.h>
#include <math.h>

typedef unsigned short u16;
typedef unsigned int u32;
typedef __attribute__((ext_vector_type(8))) short short8;
typedef __attribute__((ext_vector_type(4))) float f32x4;

#define WS_ 7
#define SS_ 3
#define NH_ 4
#define HD_ 32
#define C_ 128
#define NTOK 200704   // B*H*W = 64*56*56
#define NWIN 4096     // B * 64
#define SCALE_ 0.17677669529663687f

static __device__ __forceinline__ float bf2f(u16 u) {
    return __uint_as_float(((u32)u) << 16);
}
static __device__ __forceinline__ u16 f2bf(float f) {
    u32 u = __float_as_uint(f);
    u32 r = u + 0x7FFFu + ((u >> 16) & 1u);
    return (u16)(r >> 16);
}

// ---------------- weight transpose to bf16 [N][K] ----------------
__global__ void k_transpose(const float* __restrict__ W, u16* __restrict__ Wt, int K, int N) {
    int i = blockIdx.x * 256 + threadIdx.x;
    if (i >= K * N) return;
    int k = i / N, n = i % N;
    Wt[(size_t)n * K + k] = f2bf(W[i]);
}

// ---------------- LN1 + roll(-3,-3) + window partition ----------------
// one wave per token row; writes bf16 window-ordered [4096][49][128]
__global__ __launch_bounds__(256) void k_ln1(const float* __restrict__ x,
                                             const float* __restrict__ g,
                                             const float* __restrict__ be,
                                             u16* __restrict__ xw) {
    int lane = threadIdx.x & 63, wv = threadIdx.x >> 6;
    int t = blockIdx.x * 4 + wv;
    const float* px = x + (size_t)t * C_;
    float2 v = *(const float2*)(px + lane * 2);
    float s = v.x + v.y;
#pragma unroll
    for (int off = 1; off < 64; off <<= 1) s += __shfl_xor(s, off, 64);
    float mu = s * (1.f / 128.f);
    float dx = v.x - mu, dy = v.y - mu;
    float s2 = dx * dx + dy * dy;
#pragma unroll
    for (int off = 1; off < 64; off <<= 1) s2 += __shfl_xor(s2, off, 64);
    float rs = rsqrtf(s2 * (1.f / 128.f) + 1e-3f);
    float2 gg = *(const float2*)(g + lane * 2);
    float2 bb = *(const float2*)(be + lane * 2);
    float o0 = dx * rs * gg.x + bb.x;
    float o1 = dy * rs * gg.y + bb.y;
    // destination (shifted + partitioned)
    int b = t / 3136, p = t % 3136;
    int y = p / 56, xx = p % 56;
    int ys = y + 53; if (ys >= 56) ys -= 56;
    int xs = xx + 53; if (xs >= 56) xs -= 56;
    int w = (b << 6) | ((ys / 7) << 3) | (xs / 7);
    int n = (ys % 7) * 7 + (xs % 7);
    u16 o[2] = {f2bf(o0), f2bf(o1)};
    *(u32*)(xw + ((size_t)w * 49 + n) * C_ + lane * 2) = *(u32*)o;
}

// ---------------- generic MFMA tile: 16 rows x NO cols per wave ----------------
template <int KD, int NO>
static __device__ __forceinline__ void gemm_tile(const u16* __restrict__ A,
                                                 const u16* __restrict__ Wt,
                                                 int m0, int lane, f32x4* acc) {
    constexpr int NK = KD / 32, NN = NO / 16;
    const int row = m0 + (lane & 15);
    const int kb = (lane >> 4) * 8;
    short8 af[NK];
#pragma unroll
    for (int ks = 0; ks < NK; ++ks)
        af[ks] = *(const short8*)(A + (size_t)row * KD + ks * 32 + kb);
#pragma unroll
    for (int n = 0; n < NN; ++n) acc[n] = (f32x4){0.f, 0.f, 0.f, 0.f};
#pragma unroll
    for (int ks = 0; ks < NK; ++ks) {
#pragma unroll
        for (int n = 0; n < NN; ++n) {
            short8 bfr = *(const short8*)(Wt + (size_t)(n * 16 + (lane & 15)) * KD + ks * 32 + kb);
            acc[n] = __builtin_amdgcn_mfma_f32_16x16x32_bf16(af[ks], bfr, acc[n], 0, 0, 0);
        }
    }
}

// ---------------- QKV GEMM: [M,128] x [128,384] -> bf16 ----------------
__global__ __launch_bounds__(256) void k_qkv(const u16* __restrict__ xw,
                                             const u16* __restrict__ qkvT,
                                             const float* __restrict__ bqkv,
                                             u16* __restrict__ qkv) {
    int lane = threadIdx.x & 63, wv = threadIdx.x >> 6;
    int m0 = blockIdx.x * 64 + wv * 16;
    f32x4 acc[24];
    gemm_tile<128, 384>(xw, qkvT, m0, lane, acc);
    int colb = lane & 15, rg = lane >> 4;
#pragma unroll
    for (int n = 0; n < 24; ++n) {
        int col = n * 16 + colb;
        float bb = bqkv[col];
#pragma unroll
        for (int r = 0; r < 4; ++r) {
            size_t row = m0 + rg * 4 + r;
            qkv[row * 384 + col] = f2bf(acc[n][r] + bb);
        }
    }
}

// ---------------- window attention: 1 block/window, 1 wave/head ----------------
__global__ __launch_bounds__(256) void k_attn(const u16* __restrict__ qkv,
                                              const float* __restrict__ relTab,
                                              u16* __restrict__ outA) {
    __shared__ u16 qs[49 * 128];
    __shared__ u16 vs[49 * 128];
    __shared__ float biasl[169 * 4];
    __shared__ float pl[4][2][64];
    int tid = threadIdx.x;
    int w = blockIdx.x;
    const u16* base = qkv + (size_t)w * 49 * 384;
    for (int idx = tid; idx < 49 * 16; idx += 256) {
        int r = idx >> 4, c8 = (idx & 15) * 8;
        *(short8*)(qs + r * 128 + c8) = *(const short8*)(base + r * 384 + c8);
        *(short8*)(vs + r * 128 + c8) = *(const short8*)(base + r * 384 + 256 + c8);
    }
    for (int idx = tid; idx < 169 * 4; idx += 256) biasl[idx] = relTab[idx];
    __syncthreads();

    int lane = tid & 63, h = tid >> 6;
    int wi = w & 63, wr = wi >> 3, wc = wi & 7;
    int j = lane < 49 ? lane : 48;
    bool jvalid = lane < 49;

    // K row of this lane's key, in f32 regs
    float kf[32];
    {
        const u16* kp = base + (size_t)j * 384 + 128 + h * 32;
#pragma unroll
        for (int t4 = 0; t4 < 4; ++t4) {
            short8 kk = *(const short8*)(kp + t4 * 8);
#pragma unroll
            for (int e = 0; e < 8; ++e) kf[t4 * 8 + e] = bf2f((u16)kk[e]);
        }
    }
    // V column of this lane's output dim, in f32 regs
    int d = lane & 31;
    float vf[49];
#pragma unroll
    for (int jj = 0; jj < 49; ++jj) vf[jj] = bf2f(vs[jj * 128 + h * 32 + d]);

    int yj = j / 7, xj = j % 7;
    int gy = wr * 7 + yj, gx = wc * 7 + xj;
    int cj = (gy < 49 ? 0 : (gy < 53 ? 1 : 2)) * 3 + (gx < 49 ? 0 : (gx < 53 ? 1 : 2));

#pragma unroll 1
    for (int r0 = 0; r0 < 49; r0 += 2) {
        int r1 = (r0 + 1 < 49) ? r0 + 1 : 48;
        float s0 = 0.f, s1 = 0.f;
#pragma unroll
        for (int t4 = 0; t4 < 4; ++t4) {
            short8 q0v = *(const short8*)(qs + r0 * 128 + h * 32 + t4 * 8);
            short8 q1v = *(const short8*)(qs + r1 * 128 + h * 32 + t4 * 8);
#pragma unroll
            for (int e = 0; e < 8; ++e) {
                float kv = kf[t4 * 8 + e];
                s0 += bf2f((u16)q0v[e]) * kv;
                s1 += bf2f((u16)q1v[e]) * kv;
            }
        }
        int yi0 = r0 / 7, xi0 = r0 % 7, yi1 = r1 / 7, xi1 = r1 % 7;
        int g0y = wr * 7 + yi0, g0x = wc * 7 + xi0;
        int g1y = wr * 7 + yi1, g1x = wc * 7 + xi1;
        int c0 = (g0y < 49 ? 0 : (g0y < 53 ? 1 : 2)) * 3 + (g0x < 49 ? 0 : (g0x < 53 ? 1 : 2));
        int c1 = (g1y < 49 ? 0 : (g1y < 53 ? 1 : 2)) * 3 + (g1x < 49 ? 0 : (g1x < 53 ? 1 : 2));
        s0 = s0 * SCALE_ + biasl[((yi0 - yj + 6) * 13 + (xi0 - xj + 6)) * 4 + h] + (c0 == cj ? 0.f : -100.f);
        s1 = s1 * SCALE_ + biasl[((yi1 - yj + 6) * 13 + (xi1 - xj + 6)) * 4 + h] + (c1 == cj ? 0.f : -100.f);
        if (!jvalid) { s0 = -1e30f; s1 = -1e30f; }
        float m0 = s0, m1 = s1;
#pragma unroll
        for (int off = 32; off; off >>= 1) {
            m0 = fmaxf(m0, __shfl_xor(m0, off, 64));
            m1 = fmaxf(m1, __shfl_xor(m1, off, 64));
        }
        float e0 = jvalid ? __expf(s0 - m0) : 0.f;
        float e1 = jvalid ? __expf(s1 - m1) : 0.f;
        float t0 = e0, t1 = e1;
#pragma unroll
        for (int off = 32; off; off >>= 1) {
            t0 += __shfl_xor(t0, off, 64);
            t1 += __shfl_xor(t1, off, 64);
        }
        pl[h][0][lane] = e0 / t0;
        pl[h][1][lane] = e1 / t1;
        // same-wave LDS RAW: compiler inserts lgkmcnt wait; no barrier needed
        int half = lane >> 5;
        const float* pp = &pl[h][half][0];
        float o = 0.f;
#pragma unroll
        for (int jj = 0; jj < 49; ++jj) o += pp[jj] * vf[jj];
        int rr = half ? r1 : r0;
        if (half == 0 || r0 + 1 < 49)
            outA[((size_t)w * 49 + rr) * C_ + h * 32 + d] = f2bf(o);
    }
}

// ---------------- proj GEMM + reverse/roll + residual + LN2 ----------------
__global__ __launch_bounds__(256) void k_proj(const u16* __restrict__ attnO,
                                              const u16* __restrict__ projT,
                                              const float* __restrict__ bproj,
                                              const float* __restrict__ x_in,
                                              const float* __restrict__ g2,
                                              const float* __restrict__ be2,
                                              float* __restrict__ x1,
                                              u16* __restrict__ mOut) {
    int lane = threadIdx.x & 63, wv = threadIdx.x >> 6;
    int m0 = blockIdx.x * 64 + wv * 16;
    f32x4 acc[8];
    gemm_tile<128, 128>(attnO, projT, m0, lane, acc);
    int colb = lane & 15, rg = lane >> 4;
#pragma unroll
    for (int r = 0; r < 4; ++r) {
        int m = m0 + rg * 4 + r;
        int w = m / 49, n = m % 49;
        int b = w >> 6, wi = w & 63;
        int wr = wi >> 3, wc = wi & 7;
        int ys = wr * 7 + n / 7, xs = wc * 7 + n % 7;
        int y = ys + 3; if (y >= 56) y -= 56;
        int x = xs + 3; if (x >= 56) x -= 56;
        size_t tok = (size_t)b * 3136 + y * 56 + x;
        float v[8];
        float s = 0.f;
#pragma unroll
        for (int n2 = 0; n2 < 8; ++n2) {
            int col = n2 * 16 + colb;
            v[n2] = acc[n2][r] + bproj[col] + x_in[tok * C_ + col];
            s += v[n2];
        }
#pragma unroll
        for (int off = 1; off < 16; off <<= 1) s += __shfl_xor(s, off, 64);
        float mu = s * (1.f / 128.f);
        float s2 = 0.f;
#pragma unroll
        for (int n2 = 0; n2 < 8; ++n2) { float dd = v[n2] - mu; s2 += dd * dd; }
#pragma unroll
        for (int off = 1; off < 16; off <<= 1) s2 += __shfl_xor(s2, off, 64);
        float rs = rsqrtf(s2 * (1.f / 128.f) + 1e-3f);
#pragma unroll
        for (int n2 = 0; n2 < 8; ++n2) {
            int col = n2 * 16 + colb;
            x1[tok * C_ + col] = v[n2];
            mOut[tok * C_ + col] = f2bf((v[n2] - mu) * rs * g2[col] + be2[col]);
        }
    }
}

// ---------------- FC1 + exact GELU ----------------
__global__ __launch_bounds__(256) void k_fc1(const u16* __restrict__ mIn,
                                             const u16* __restrict__ fc1T,
                                             const float* __restrict__ b1,
                                             u16* __restrict__ h1) {
    int lane = threadIdx.x & 63, wv = threadIdx.x >> 6;
    int m0 = blockIdx.x * 64 + wv * 16;
    f32x4 acc[32];
    gemm_tile<128, 512>(mIn, fc1T, m0, lane, acc);
    int colb = lane & 15, rg = lane >> 4;
#pragma unroll
    for (int n = 0; n < 32; ++n) {
        int col = n * 16 + colb;
        float bb = b1[col];
#pragma unroll
        for (int r = 0; r < 4; ++r) {
            size_t row = m0 + rg * 4 + r;
            float t = acc[n][r] + bb;
            float g = 0.5f * t * (1.f + erff(t * 0.70710678118654752f));
            h1[row * 512 + col] = f2bf(g);
        }
    }
}

// ---------------- FC2 + final residual ----------------
__global__ __launch_bounds__(256) void k_fc2(const u16* __restrict__ h1,
                                             const u16* __restrict__ fc2T,
                                             const float* __restrict__ b2,
                                             const float* __restrict__ x1,
                                             float* __restrict__ out) {
    int lane = threadIdx.x & 63, wv = threadIdx.x >> 6;
    int m0 = blockIdx.x * 64 + wv * 16;
    f32x4 acc[8];
    gemm_tile<512, 128>(h1, fc2T, m0, lane, acc);
    int colb = lane & 15, rg = lane >> 4;
#pragma unroll
    for (int n = 0; n < 8; ++n) {
        int col = n * 16 + colb;
        float bb = b2[col];
#pragma unroll
        for (int r = 0; r < 4; ++r) {
            size_t row = m0 + rg * 4 + r;
            out[row * C_ + col] = x1[row * C_ + col] + acc[n][r] + bb;
        }
    }
}

extern "C" void kernel_launch(void* const* d_in, const int* in_sizes, int n_in,
                              void* d_out, int out_size, void* d_ws, size_t ws_size,
                              hipStream_t stream) {
    const float* x    = (const float*)d_in[0];
    const float* g1   = (const float*)d_in[1];
    const float* be1  = (const float*)d_in[2];
    const float* Wqkv = (const float*)d_in[3];
    const float* bqkv = (const float*)d_in[4];
    const float* relT = (const float*)d_in[5];
    const float* Wproj= (const float*)d_in[6];
    const float* bproj= (const float*)d_in[7];
    const float* g2   = (const float*)d_in[8];
    const float* be2  = (const float*)d_in[9];
    const float* Wfc1 = (const float*)d_in[10];
    const float* bfc1 = (const float*)d_in[11];
    const float* Wfc2 = (const float*)d_in[12];
    const float* bfc2 = (const float*)d_in[13];
    float* out = (float*)d_out;
    char* ws = (char*)d_ws;

    // workspace layout (peak ~361.2 MB), aliased by lifetime:
    u16* xw    = (u16*)(ws + 0);              // 51,380,224 B   (dead after k_qkv)
    u16* qkv   = (u16*)(ws + 52428800ULL);    // 154,140,672 B  (dead after k_attn)
    u16* attnO = (u16*)(ws + 0);              // 51,380,224 B   (overwrites xw; dead after k_proj)
    float* x1  = (float*)(ws + 206569472ULL); // 102,760,448 B  (lives to k_fc2)
    u16* mbuf  = (u16*)(ws + 309329920ULL);   // 51,380,224 B
    u16* h1    = (u16*)(ws + 0);              // 205,520,896 B  (overwrites xw/qkv/attnO)
    u16* qkvT  = (u16*)(ws + 360710144ULL);   // transposed bf16 weights
    u16* projT = qkvT + 384 * 128;
    u16* fc1T  = projT + 128 * 128;
    u16* fc2T  = fc1T + 512 * 128;

    k_transpose<<<dim3((128 * 384 + 255) / 256), dim3(256), 0, stream>>>(Wqkv, qkvT, 128, 384);
    k_transpose<<<dim3((128 * 128 + 255) / 256), dim3(256), 0, stream>>>(Wproj, projT, 128, 128);
    k_transpose<<<dim3((128 * 512 + 255) / 256), dim3(256), 0, stream>>>(Wfc1, fc1T, 128, 512);
    k_transpose<<<dim3((512 * 128 + 255) / 256), dim3(256), 0, stream>>>(Wfc2, fc2T, 512, 128);

    k_ln1<<<dim3(NTOK / 4), dim3(256), 0, stream>>>(x, g1, be1, xw);
    k_qkv<<<dim3(NTOK / 64), dim3(256), 0, stream>>>(xw, qkvT, bqkv, qkv);
    k_attn<<<dim3(NWIN), dim3(256), 0, stream>>>(qkv, relT, attnO);
    k_proj<<<dim3(NTOK / 64), dim3(256), 0, stream>>>(attnO, projT, bproj, x, g2, be2, x1, mbuf);
    k_fc1<<<dim3(NTOK / 64), dim3(256), 0, stream>>>(mbuf, fc1T, bfc1, h1);
    k_fc2<<<dim3(NTOK / 64), dim3(256), 0, stream>>>(h1, fc2T, bfc2, x1, out);
}

// Round 2
// 800.760 us; speedup vs baseline: 1.4349x; 1.4349x over previous
//
#include <hip/hip_runtime.h>
#include <math.h>

typedef unsigned short u16;
typedef unsigned int u32;
typedef __attribute__((ext_vector_type(8))) short short8;
typedef __attribute__((ext_vector_type(4))) float f32x4;

#define WS_ 7
#define SS_ 3
#define NH_ 4
#define HD_ 32
#define C_ 128
#define NTOK 200704   // B*H*W = 64*56*56
#define NMT  12544    // NTOK/16 M-tiles
#define NWIN 4096     // B * 64
#define SCALE_ 0.17677669529663687f

static __device__ __forceinline__ float bf2f(u16 u) {
    return __uint_as_float(((u32)u) << 16);
}
static __device__ __forceinline__ u16 f2bf(float f) {
    u32 u = __float_as_uint(f);
    u32 r = u + 0x7FFFu + ((u >> 16) & 1u);
    return (u16)(r >> 16);
}

// ---------------- weight transpose to bf16 [N][K] ----------------
__global__ void k_transpose(const float* __restrict__ W, u16* __restrict__ Wt, int K, int N) {
    int i = blockIdx.x * 256 + threadIdx.x;
    if (i >= K * N) return;
    int k = i / N, n = i % N;
    Wt[(size_t)n * K + k] = f2bf(W[i]);
}

// ---------------- LN1 + roll(-3,-3) + window partition ----------------
__global__ __launch_bounds__(256) void k_ln1(const float* __restrict__ x,
                                             const float* __restrict__ g,
                                             const float* __restrict__ be,
                                             u16* __restrict__ xw) {
    int lane = threadIdx.x & 63, wv = threadIdx.x >> 6;
    int t = blockIdx.x * 4 + wv;
    const float* px = x + (size_t)t * C_;
    float2 v = *(const float2*)(px + lane * 2);
    float s = v.x + v.y;
#pragma unroll
    for (int off = 1; off < 64; off <<= 1) s += __shfl_xor(s, off, 64);
    float mu = s * (1.f / 128.f);
    float dx = v.x - mu, dy = v.y - mu;
    float s2 = dx * dx + dy * dy;
#pragma unroll
    for (int off = 1; off < 64; off <<= 1) s2 += __shfl_xor(s2, off, 64);
    float rs = rsqrtf(s2 * (1.f / 128.f) + 1e-3f);
    float2 gg = *(const float2*)(g + lane * 2);
    float2 bb = *(const float2*)(be + lane * 2);
    float o0 = dx * rs * gg.x + bb.x;
    float o1 = dy * rs * gg.y + bb.y;
    int b = t / 3136, p = t % 3136;
    int y = p / 56, xx = p % 56;
    int ys = y + 53; if (ys >= 56) ys -= 56;
    int xs = xx + 53; if (xs >= 56) xs -= 56;
    int w = (b << 6) | ((ys / 7) << 3) | (xs / 7);
    int n = (ys % 7) * 7 + (xs % 7);
    u16 o[2] = {f2bf(o0), f2bf(o1)};
    *(u32*)(xw + ((size_t)w * 49 + n) * C_ + lane * 2) = *(u32*)o;
}

// ---------------- weight-stationary MFMA helpers ----------------
// B-fragments held in registers for a wave's N-slice; loaded ONCE per kernel.
template <int KD, int NN>
static __device__ __forceinline__ void load_bfrag(const u16* __restrict__ Wt, int col0, int lane,
                                                  short8 (&bf)[NN][KD / 32]) {
    constexpr int NK = KD / 32;
    const int colb = lane & 15, kb = (lane >> 4) * 8;
#pragma unroll
    for (int n = 0; n < NN; ++n)
#pragma unroll
        for (int ks = 0; ks < NK; ++ks)
            bf[n][ks] = *(const short8*)(Wt + (size_t)(col0 + n * 16 + colb) * KD + ks * 32 + kb);
}

template <int KD, int NN>
static __device__ __forceinline__ void mm_tile(const u16* __restrict__ A, int m0, int lane,
                                               const short8 (&bf)[NN][KD / 32], f32x4 (&acc)[NN]) {
    constexpr int NK = KD / 32;
    const int row = m0 + (lane & 15), kb = (lane >> 4) * 8;
#pragma unroll
    for (int n = 0; n < NN; ++n) acc[n] = (f32x4){0.f, 0.f, 0.f, 0.f};
#pragma unroll
    for (int ks = 0; ks < NK; ++ks) {
        short8 af = *(const short8*)(A + (size_t)row * KD + ks * 32 + kb);
#pragma unroll
        for (int n = 0; n < NN; ++n)
            acc[n] = __builtin_amdgcn_mfma_f32_16x16x32_bf16(af, bf[n][ks], acc[n], 0, 0, 0);
    }
}

// ---------------- QKV GEMM: [M,128] x [128,384], wave owns 96 cols ----------------
__global__ __launch_bounds__(256) void k_qkv(const u16* __restrict__ xw,
                                             const u16* __restrict__ qkvT,
                                             const float* __restrict__ bqkv,
                                             u16* __restrict__ qkv) {
    int lane = threadIdx.x & 63, wv = threadIdx.x >> 6;
    int col0 = wv * 96;
    int colb = lane & 15, rg = lane >> 4;
    short8 bf[6][4];
    load_bfrag<128, 6>(qkvT, col0, lane, bf);
    float bias[6];
#pragma unroll
    for (int n = 0; n < 6; ++n) bias[n] = bqkv[col0 + n * 16 + colb];
    for (int mt = blockIdx.x; mt < NMT; mt += gridDim.x) {
        f32x4 acc[6];
        mm_tile<128, 6>(xw, mt * 16, lane, bf, acc);
#pragma unroll
        for (int n = 0; n < 6; ++n) {
            int col = col0 + n * 16 + colb;
#pragma unroll
            for (int r = 0; r < 4; ++r) {
                size_t row = mt * 16 + rg * 4 + r;
                qkv[row * 384 + col] = f2bf(acc[n][r] + bias[n]);
            }
        }
    }
}

// ---------------- window attention: 1 block/window, 1 wave/head ----------------
__global__ __launch_bounds__(256) void k_attn(const u16* __restrict__ qkv,
                                              const float* __restrict__ relTab,
                                              u16* __restrict__ outA) {
    __shared__ u16 qs[49 * 128];
    __shared__ u16 vs[49 * 128];
    __shared__ float biasl[169 * 4];
    __shared__ float pl[4][2][64];
    int tid = threadIdx.x;
    int w = blockIdx.x;
    const u16* base = qkv + (size_t)w * 49 * 384;
    for (int idx = tid; idx < 49 * 16; idx += 256) {
        int r = idx >> 4, c8 = (idx & 15) * 8;
        *(short8*)(qs + r * 128 + c8) = *(const short8*)(base + r * 384 + c8);
        *(short8*)(vs + r * 128 + c8) = *(const short8*)(base + r * 384 + 256 + c8);
    }
    for (int idx = tid; idx < 169 * 4; idx += 256) biasl[idx] = relTab[idx];
    __syncthreads();

    int lane = tid & 63, h = tid >> 6;
    int wi = w & 63, wr = wi >> 3, wc = wi & 7;
    int j = lane < 49 ? lane : 48;
    bool jvalid = lane < 49;

    float kf[32];
    {
        const u16* kp = base + (size_t)j * 384 + 128 + h * 32;
#pragma unroll
        for (int t4 = 0; t4 < 4; ++t4) {
            short8 kk = *(const short8*)(kp + t4 * 8);
#pragma unroll
            for (int e = 0; e < 8; ++e) kf[t4 * 8 + e] = bf2f((u16)kk[e]);
        }
    }
    int d = lane & 31;
    float vf[49];
#pragma unroll
    for (int jj = 0; jj < 49; ++jj) vf[jj] = bf2f(vs[jj * 128 + h * 32 + d]);

    int yj = j / 7, xj = j % 7;
    int gy = wr * 7 + yj, gx = wc * 7 + xj;
    int cj = (gy < 49 ? 0 : (gy < 53 ? 1 : 2)) * 3 + (gx < 49 ? 0 : (gx < 53 ? 1 : 2));

#pragma unroll 1
    for (int r0 = 0; r0 < 49; r0 += 2) {
        int r1 = (r0 + 1 < 49) ? r0 + 1 : 48;
        float s0 = 0.f, s1 = 0.f;
#pragma unroll
        for (int t4 = 0; t4 < 4; ++t4) {
            short8 q0v = *(const short8*)(qs + r0 * 128 + h * 32 + t4 * 8);
            short8 q1v = *(const short8*)(qs + r1 * 128 + h * 32 + t4 * 8);
#pragma unroll
            for (int e = 0; e < 8; ++e) {
                float kv = kf[t4 * 8 + e];
                s0 += bf2f((u16)q0v[e]) * kv;
                s1 += bf2f((u16)q1v[e]) * kv;
            }
        }
        int yi0 = r0 / 7, xi0 = r0 % 7, yi1 = r1 / 7, xi1 = r1 % 7;
        int g0y = wr * 7 + yi0, g0x = wc * 7 + xi0;
        int g1y = wr * 7 + yi1, g1x = wc * 7 + xi1;
        int c0 = (g0y < 49 ? 0 : (g0y < 53 ? 1 : 2)) * 3 + (g0x < 49 ? 0 : (g0x < 53 ? 1 : 2));
        int c1 = (g1y < 49 ? 0 : (g1y < 53 ? 1 : 2)) * 3 + (g1x < 49 ? 0 : (g1x < 53 ? 1 : 2));
        s0 = s0 * SCALE_ + biasl[((yi0 - yj + 6) * 13 + (xi0 - xj + 6)) * 4 + h] + (c0 == cj ? 0.f : -100.f);
        s1 = s1 * SCALE_ + biasl[((yi1 - yj + 6) * 13 + (xi1 - xj + 6)) * 4 + h] + (c1 == cj ? 0.f : -100.f);
        if (!jvalid) { s0 = -1e30f; s1 = -1e30f; }
        float m0 = s0, m1 = s1;
#pragma unroll
        for (int off = 32; off; off >>= 1) {
            m0 = fmaxf(m0, __shfl_xor(m0, off, 64));
            m1 = fmaxf(m1, __shfl_xor(m1, off, 64));
        }
        float e0 = jvalid ? __expf(s0 - m0) : 0.f;
        float e1 = jvalid ? __expf(s1 - m1) : 0.f;
        float t0 = e0, t1 = e1;
#pragma unroll
        for (int off = 32; off; off >>= 1) {
            t0 += __shfl_xor(t0, off, 64);
            t1 += __shfl_xor(t1, off, 64);
        }
        pl[h][0][lane] = e0 / t0;
        pl[h][1][lane] = e1 / t1;
        int half = lane >> 5;
        const float* pp = &pl[h][half][0];
        float o = 0.f;
#pragma unroll
        for (int jj = 0; jj < 49; ++jj) o += pp[jj] * vf[jj];
        int rr = half ? r1 : r0;
        if (half == 0 || r0 + 1 < 49)
            outA[((size_t)w * 49 + rr) * C_ + h * 32 + d] = f2bf(o);
    }
}

// ---------------- proj GEMM + reverse/roll + residual + LN2 ----------------
// wave owns full 128 cols (needed for in-wave LN row reduction); wave-per-M-tile.
__global__ __launch_bounds__(256) void k_proj(const u16* __restrict__ attnO,
                                              const u16* __restrict__ projT,
                                              const float* __restrict__ bproj,
                                              const float* __restrict__ x_in,
                                              const float* __restrict__ g2,
                                              const float* __restrict__ be2,
                                              float* __restrict__ x1,
                                              u16* __restrict__ mOut) {
    int lane = threadIdx.x & 63, wv = threadIdx.x >> 6;
    int colb = lane & 15, rg = lane >> 4;
    short8 bf[8][4];
    load_bfrag<128, 8>(projT, 0, lane, bf);
    float bias[8], g2r[8], be2r[8];
#pragma unroll
    for (int n = 0; n < 8; ++n) {
        bias[n] = bproj[n * 16 + colb];
        g2r[n] = g2[n * 16 + colb];
        be2r[n] = be2[n * 16 + colb];
    }
    int wgid = blockIdx.x * 4 + wv, nw = gridDim.x * 4;
    for (int mt = wgid; mt < NMT; mt += nw) {
        f32x4 acc[8];
        mm_tile<128, 8>(attnO, mt * 16, lane, bf, acc);
#pragma unroll
        for (int r = 0; r < 4; ++r) {
            int m = mt * 16 + rg * 4 + r;
            int w = m / 49, n = m % 49;
            int b = w >> 6, wi = w & 63;
            int wr = wi >> 3, wc = wi & 7;
            int ys = wr * 7 + n / 7, xs = wc * 7 + n % 7;
            int y = ys + 3; if (y >= 56) y -= 56;
            int x = xs + 3; if (x >= 56) x -= 56;
            size_t tok = (size_t)b * 3136 + y * 56 + x;
            float v[8];
            float s = 0.f;
#pragma unroll
            for (int n2 = 0; n2 < 8; ++n2) {
                int col = n2 * 16 + colb;
                v[n2] = acc[n2][r] + bias[n2] + x_in[tok * C_ + col];
                s += v[n2];
            }
#pragma unroll
            for (int off = 1; off < 16; off <<= 1) s += __shfl_xor(s, off, 64);
            float mu = s * (1.f / 128.f);
            float s2 = 0.f;
#pragma unroll
            for (int n2 = 0; n2 < 8; ++n2) { float dd = v[n2] - mu; s2 += dd * dd; }
#pragma unroll
            for (int off = 1; off < 16; off <<= 1) s2 += __shfl_xor(s2, off, 64);
            float rs = rsqrtf(s2 * (1.f / 128.f) + 1e-3f);
#pragma unroll
            for (int n2 = 0; n2 < 8; ++n2) {
                int col = n2 * 16 + colb;
                x1[tok * C_ + col] = v[n2];
                mOut[tok * C_ + col] = f2bf((v[n2] - mu) * rs * g2r[n2] + be2r[n2]);
            }
        }
    }
}

// ---------------- FC1 + exact GELU: [M,128] x [128,512], wave owns 128 cols ----------------
__global__ __launch_bounds__(256) void k_fc1(const u16* __restrict__ mIn,
                                             const u16* __restrict__ fc1T,
                                             const float* __restrict__ b1,
                                             u16* __restrict__ h1) {
    int lane = threadIdx.x & 63, wv = threadIdx.x >> 6;
    int col0 = wv * 128;
    int colb = lane & 15, rg = lane >> 4;
    short8 bf[8][4];
    load_bfrag<128, 8>(fc1T, col0, lane, bf);
    float bias[8];
#pragma unroll
    for (int n = 0; n < 8; ++n) bias[n] = b1[col0 + n * 16 + colb];
    for (int mt = blockIdx.x; mt < NMT; mt += gridDim.x) {
        f32x4 acc[8];
        mm_tile<128, 8>(mIn, mt * 16, lane, bf, acc);
#pragma unroll
        for (int n = 0; n < 8; ++n) {
            int col = col0 + n * 16 + colb;
#pragma unroll
            for (int r = 0; r < 4; ++r) {
                size_t row = mt * 16 + rg * 4 + r;
                float t = acc[n][r] + bias[n];
                float g = 0.5f * t * (1.f + erff(t * 0.70710678118654752f));
                h1[row * 512 + col] = f2bf(g);
            }
        }
    }
}

// ---------------- FC2 + final residual: [M,512] x [512,128], wave owns 32 cols ----------------
__global__ __launch_bounds__(256) void k_fc2(const u16* __restrict__ h1,
                                             const u16* __restrict__ fc2T,
                                             const float* __restrict__ b2,
                                             const float* __restrict__ x1,
                                             float* __restrict__ out) {
    int lane = threadIdx.x & 63, wv = threadIdx.x >> 6;
    int col0 = wv * 32;
    int colb = lane & 15, rg = lane >> 4;
    short8 bf[2][16];
    load_bfrag<512, 2>(fc2T, col0, lane, bf);
    float bias[2];
#pragma unroll
    for (int n = 0; n < 2; ++n) bias[n] = b2[col0 + n * 16 + colb];
    for (int mt = blockIdx.x; mt < NMT; mt += gridDim.x) {
        f32x4 acc[2];
        mm_tile<512, 2>(h1, mt * 16, lane, bf, acc);
#pragma unroll
        for (int n = 0; n < 2; ++n) {
            int col = col0 + n * 16 + colb;
#pragma unroll
            for (int r = 0; r < 4; ++r) {
                size_t row = mt * 16 + rg * 4 + r;
                out[row * C_ + col] = x1[row * C_ + col] + acc[n][r] + bias[n];
            }
        }
    }
}

extern "C" void kernel_launch(void* const* d_in, const int* in_sizes, int n_in,
                              void* d_out, int out_size, void* d_ws, size_t ws_size,
                              hipStream_t stream) {
    const float* x    = (const float*)d_in[0];
    const float* g1   = (const float*)d_in[1];
    const float* be1  = (const float*)d_in[2];
    const float* Wqkv = (const float*)d_in[3];
    const float* bqkv = (const float*)d_in[4];
    const float* relT = (const float*)d_in[5];
    const float* Wproj= (const float*)d_in[6];
    const float* bproj= (const float*)d_in[7];
    const float* g2   = (const float*)d_in[8];
    const float* be2  = (const float*)d_in[9];
    const float* Wfc1 = (const float*)d_in[10];
    const float* bfc1 = (const float*)d_in[11];
    const float* Wfc2 = (const float*)d_in[12];
    const float* bfc2 = (const float*)d_in[13];
    float* out = (float*)d_out;
    char* ws = (char*)d_ws;

    u16* xw    = (u16*)(ws + 0);              // dead after k_qkv
    u16* qkv   = (u16*)(ws + 52428800ULL);    // dead after k_attn
    u16* attnO = (u16*)(ws + 0);              // overwrites xw; dead after k_proj
    float* x1  = (float*)(ws + 206569472ULL); // lives to k_fc2
    u16* mbuf  = (u16*)(ws + 309329920ULL);
    u16* h1    = (u16*)(ws + 0);              // overwrites xw/qkv/attnO
    u16* qkvT  = (u16*)(ws + 360710144ULL);
    u16* projT = qkvT + 384 * 128;
    u16* fc1T  = projT + 128 * 128;
    u16* fc2T  = fc1T + 512 * 128;

    k_transpose<<<dim3((128 * 384 + 255) / 256), dim3(256), 0, stream>>>(Wqkv, qkvT, 128, 384);
    k_transpose<<<dim3((128 * 128 + 255) / 256), dim3(256), 0, stream>>>(Wproj, projT, 128, 128);
    k_transpose<<<dim3((128 * 512 + 255) / 256), dim3(256), 0, stream>>>(Wfc1, fc1T, 128, 512);
    k_transpose<<<dim3((512 * 128 + 255) / 256), dim3(256), 0, stream>>>(Wfc2, fc2T, 512, 128);

    k_ln1<<<dim3(NTOK / 4), dim3(256), 0, stream>>>(x, g1, be1, xw);
    k_qkv<<<dim3(1024), dim3(256), 0, stream>>>(xw, qkvT, bqkv, qkv);
    k_attn<<<dim3(NWIN), dim3(256), 0, stream>>>(qkv, relT, attnO);
    k_proj<<<dim3(768), dim3(256), 0, stream>>>(attnO, projT, bproj, x, g2, be2, x1, mbuf);
    k_fc1<<<dim3(1024), dim3(256), 0, stream>>>(mbuf, fc1T, bfc1, h1);
    k_fc2<<<dim3(1024), dim3(256), 0, stream>>>(h1, fc2T, bfc2, x1, out);
}